// Round 1
// baseline (130.309 us; speedup 1.0000x reference)
//
#include <hip/hip_runtime.h>

// Problem constants
#define BB 8
#define CI 64
#define CO 64
#define NV 40962
#define KN 7
#define KKD 448   // CI*KN

typedef unsigned short u16;
typedef unsigned int u32;

typedef __bf16 bf16x8 __attribute__((ext_vector_type(8)));
typedef float f32x16 __attribute__((ext_vector_type(16)));

__device__ inline u16 f2bf(float f) {
    u32 u = __builtin_bit_cast(u32, f);
    u32 r = (u + 0x7FFFu + ((u >> 16) & 1u)) >> 16;  // RNE
    return (u16)r;
}

// ---------------------------------------------------------------------------
// Kernel 1: transpose + bf16 cast:  x[b][c][n] f32  ->  xT[b][n][c] bf16
// grid (ceil(NV/64)=641, 8), block 256
// ---------------------------------------------------------------------------
__global__ void transpose_x(const float* __restrict__ x, u16* __restrict__ xT) {
    __shared__ u16 tile[64][72];  // pad to 144B rows (16B-aligned for uint4 reads)
    const int b = blockIdx.y;
    const int n0 = blockIdx.x * 64;
    const int tid = threadIdx.x;

    // read coalesced along n, write transposed into LDS
#pragma unroll
    for (int i = 0; i < 16; ++i) {
        int flat = i * 256 + tid;       // 0..4095
        int c = flat >> 6;
        int nn = flat & 63;
        int n = n0 + nn;
        if (n < NV) {
            float v = x[((size_t)b * CI + c) * NV + n];
            tile[nn][c] = f2bf(v);
        }
    }
    __syncthreads();

    // write coalesced along c (8 bf16 = 16B per lane)
#pragma unroll
    for (int i = 0; i < 2; ++i) {
        int flat8 = i * 256 + tid;      // chunk id 0..511
        int nn = flat8 >> 3;
        int c0 = (flat8 & 7) * 8;
        int n = n0 + nn;
        if (n < NV) {
            uint4 v = *(const uint4*)&tile[nn][c0];
            *(uint4*)&xT[((size_t)b * NV + n) * CI + c0] = v;
        }
    }
}

// ---------------------------------------------------------------------------
// Kernel 2: pack W into MFMA A-fragment order (bf16)
// Wp[o][kk] = W[o][c*7 + kn]  with kk = kn*64 + c   (kn = kk>>6, c = kk&63)
// Wf[((rg*28+s)*64+lane)*8+j] = Wp[rg*32+(lane&31)][s*16 + (lane>>5)*8 + j]
// grid 112 blocks x 256 threads  (28672 elements)
// ---------------------------------------------------------------------------
__global__ void pack_w(const float* __restrict__ W, u16* __restrict__ Wf) {
    int e = blockIdx.x * 256 + threadIdx.x;
    if (e < 2 * 28 * 64 * 8) {
        int j = e & 7;
        int lane = (e >> 3) & 63;
        int sg = e >> 9;            // rg*28 + s
        int s = sg % 28;
        int rg = sg / 28;
        int o = rg * 32 + (lane & 31);
        int kk = s * 16 + ((lane >> 5) << 3) + j;
        int kn = kk >> 6;
        int c = kk & 63;
        Wf[e] = f2bf(W[o * KKD + c * KN + kn]);
    }
}

// ---------------------------------------------------------------------------
// Kernel 3: main gather + MFMA GEMM.
// grid (ceil(NV/128)=321, 8), block 512 = 8 waves = 2 row-groups x 4 col-groups
// wave (rg, cg): output rows o in [rg*32, rg*32+32), vertices n0+cg*32..+31
// A (W frags) in registers; B gathered global->reg; 28 x mfma_f32_32x32x16_bf16
// ---------------------------------------------------------------------------
__global__ __launch_bounds__(512, 2) void conv_mfma(
    const u16* __restrict__ xT, const u16* __restrict__ Wf,
    const int* __restrict__ idx, const float* __restrict__ bias,
    float* __restrict__ out) {
    const int b = blockIdx.y;
    const int n0 = blockIdx.x * 128;
    const int tid = threadIdx.x;
    const int lane = tid & 63;
    const int w = tid >> 6;
    const int rg = w & 1;
    const int cg = w >> 1;
    const int col = lane & 31;
    const int half = lane >> 5;

    const int v = n0 + cg * 32 + col;
    const int nn = (v < NV) ? v : (NV - 1);

    // neighbor indices for this lane's vertex
    int jarr[7];
#pragma unroll
    for (int k = 0; k < KN; ++k) jarr[k] = idx[nn * KN + k];

    // A fragments: 28 x 16B per lane (112 VGPRs)
    uint4 a[28];
    const uint4* wfv = (const uint4*)Wf;
#pragma unroll
    for (int s = 0; s < 28; ++s) a[s] = wfv[(rg * 28 + s) * 64 + lane];

    const u16* xb = xT + (size_t)b * NV * CI;
    const int hoff = half * 8;  // bf16 elements

    f32x16 acc{};

    // B-fragment address for step s: xb + jarr[s>>2]*64 + (s&3)*16 + hoff
    uint4 bs[8];
#pragma unroll
    for (int s = 0; s < 8; ++s) {
        bs[s] = *(const uint4*)(xb + (size_t)jarr[s >> 2] * CI + (s & 3) * 16 + hoff);
    }
#pragma unroll
    for (int s = 0; s < 28; ++s) {
        uint4 bcur = bs[s & 7];
        if (s + 8 < 28) {
            int s2 = s + 8;
            bs[s & 7] = *(const uint4*)(xb + (size_t)jarr[s2 >> 2] * CI + (s2 & 3) * 16 + hoff);
        }
        acc = __builtin_amdgcn_mfma_f32_32x32x16_bf16(
            __builtin_bit_cast(bf16x8, a[s]),
            __builtin_bit_cast(bf16x8, bcur), acc, 0, 0, 0);
    }

    if (v < NV) {
        float* ob = out + (size_t)b * CO * NV + v;
#pragma unroll
        for (int r = 0; r < 16; ++r) {
            int row = (r & 3) + 8 * (r >> 2) + 4 * half;
            int o = rg * 32 + row;
            ob[(size_t)o * NV] = acc[r] + bias[o];
        }
    }
}

// ---------------------------------------------------------------------------
// Fallback (if ws too small): direct fp32 compute, slow but correct.
// grid (ceil(NV/4), 8), block 256: o = tid>>2, vi = tid&3
// ---------------------------------------------------------------------------
__global__ void naive_conv(const float* __restrict__ x, const int* __restrict__ idx,
                           const float* __restrict__ W, const float* __restrict__ bias,
                           float* __restrict__ out) {
    const int b = blockIdx.y;
    const int n = blockIdx.x * 4 + (threadIdx.x & 3);
    const int o = threadIdx.x >> 2;
    if (n >= NV) return;
    float acc = bias[o];
    const float* xb = x + (size_t)b * CI * NV;
    const float* wo = W + o * KKD;
    for (int k = 0; k < KN; ++k) {
        int j = idx[n * KN + k];
        for (int c = 0; c < CI; ++c)
            acc += xb[(size_t)c * NV + j] * wo[c * KN + k];
    }
    out[((size_t)b * CO + o) * NV + n] = acc;
}

// ---------------------------------------------------------------------------
extern "C" void kernel_launch(void* const* d_in, const int* in_sizes, int n_in,
                              void* d_out, int out_size, void* d_ws, size_t ws_size,
                              hipStream_t stream) {
    const float* x    = (const float*)d_in[0];
    const int*   idx  = (const int*)d_in[1];
    const float* W    = (const float*)d_in[2];
    const float* bias = (const float*)d_in[3];
    float* out = (float*)d_out;

    const size_t xT_bytes = (size_t)BB * NV * CI * 2;       // 41,945,088
    const size_t wf_bytes = (size_t)2 * 28 * 64 * 8 * 2;    // 57,344
    const size_t need = xT_bytes + wf_bytes;

    if (ws_size >= need) {
        u16* xT = (u16*)d_ws;
        u16* Wf = (u16*)((char*)d_ws + xT_bytes);
        transpose_x<<<dim3((NV + 63) / 64, BB), 256, 0, stream>>>(x, xT);
        pack_w<<<dim3(112), 256, 0, stream>>>(W, Wf);
        conv_mfma<<<dim3((NV + 127) / 128, BB), 512, 0, stream>>>(xT, Wf, idx, bias, out);
    } else {
        naive_conv<<<dim3((NV + 3) / 4, BB), 256, 0, stream>>>(x, idx, W, bias, out);
    }
}

// Round 2
// 83.115 us; speedup vs baseline: 1.5678x; 1.5678x over previous
//
#include <hip/hip_runtime.h>

// Problem constants
#define BB 8
#define CI 64
#define CO 64
#define NV 40962
#define KN 7
#define KKD 448   // CI*KN

typedef unsigned short u16;
typedef unsigned int u32;

typedef __bf16 bf16x8 __attribute__((ext_vector_type(8)));
typedef float f32x16 __attribute__((ext_vector_type(16)));

__device__ inline u16 f2bf(float f) {
    u32 u = __builtin_bit_cast(u32, f);
    u32 r = (u + 0x7FFFu + ((u >> 16) & 1u)) >> 16;  // RNE
    return (u16)r;
}

// ---------------------------------------------------------------------------
// Kernel 1: transpose + bf16 cast:  x[b][c][n] f32  ->  xT[b][n][c] bf16
// ---------------------------------------------------------------------------
__global__ void transpose_x(const float* __restrict__ x, u16* __restrict__ xT) {
    __shared__ u16 tile[64][72];
    const int b = blockIdx.y;
    const int n0 = blockIdx.x * 64;
    const int tid = threadIdx.x;

#pragma unroll
    for (int i = 0; i < 16; ++i) {
        int flat = i * 256 + tid;
        int c = flat >> 6;
        int nn = flat & 63;
        int n = n0 + nn;
        if (n < NV) {
            float v = x[((size_t)b * CI + c) * NV + n];
            tile[nn][c] = f2bf(v);
        }
    }
    __syncthreads();

#pragma unroll
    for (int i = 0; i < 2; ++i) {
        int flat8 = i * 256 + tid;
        int nn = flat8 >> 3;
        int c0 = (flat8 & 7) * 8;
        int n = n0 + nn;
        if (n < NV) {
            uint4 v = *(const uint4*)&tile[nn][c0];
            *(uint4*)&xT[((size_t)b * NV + n) * CI + c0] = v;
        }
    }
}

// ---------------------------------------------------------------------------
// Kernel 2: pack W into MFMA A-fragment order (bf16)
// Wf[((rg*28+s)*64+lane)*8+j] = W[o, c*7+kn]  with o=rg*32+(lane&31),
//   kk = s*16 + (lane>>5)*8 + j,  kn = kk>>6, c = kk&63   (s = k*4+sub)
// ---------------------------------------------------------------------------
__global__ void pack_w(const float* __restrict__ W, u16* __restrict__ Wf) {
    int e = blockIdx.x * 256 + threadIdx.x;
    if (e < 2 * 28 * 64 * 8) {
        int j = e & 7;
        int lane = (e >> 3) & 63;
        int sg = e >> 9;
        int s = sg % 28;
        int rg = sg / 28;
        int o = rg * 32 + (lane & 31);
        int kk = s * 16 + ((lane >> 5) << 3) + j;
        int kn = kk >> 6;
        int c = kk & 63;
        Wf[e] = f2bf(W[o * KKD + c * KN + kn]);
    }
}

// ---------------------------------------------------------------------------
// Kernel 3: gather (coalesced, LDS-staged, double-buffered) + MFMA GEMM.
// grid (ceil(NV/128)=321, 8), block 512 = 8 waves = 2 row-groups x 4 col-groups
// Per k-neighbor: stage G[128 vertices][64 ch] bf16 (16 KB) into LDS with
// XOR swizzle; each staging load instruction reads 8 full 128B rows
// (8 lanes x 16B contiguous per row) -> coalesced.
// ---------------------------------------------------------------------------
__global__ __launch_bounds__(512, 4) void conv_mfma(
    const u16* __restrict__ xT, const u16* __restrict__ Wf,
    const int* __restrict__ idx, const float* __restrict__ bias,
    float* __restrict__ out) {
    __shared__ alignas(16) u16 g[2][128 * 64];   // 2 x 16 KB, XOR-swizzled

    const int b = blockIdx.y;
    const int n0 = blockIdx.x * 128;
    const int tid = threadIdx.x;
    const int lane = tid & 63;
    const int w = tid >> 6;
    const int rg = w & 1;
    const int cg = w >> 1;
    const int col = lane & 31;
    const int half = lane >> 5;

    const u16* xb = xT + (size_t)b * NV * CI;

    // ---- staging geometry: thread t stages 16B chunk q of rows sr0, sr0+64
    const int sr0 = tid >> 3;          // 0..63
    const int q = tid & 7;             // 16B chunk within 128B row
    int rr0 = n0 + sr0;       if (rr0 >= NV) rr0 = NV - 1;
    int rr1 = n0 + 64 + sr0;  if (rr1 >= NV) rr1 = NV - 1;

    int j0[KN], j1[KN];
#pragma unroll
    for (int k = 0; k < KN; ++k) {
        j0[k] = idx[(size_t)rr0 * KN + k];
        j1[k] = idx[(size_t)rr1 * KN + k];
    }

    // LDS write byte offsets (swizzle: slot q ^= row&7; (64+sr0)&7 == sr0&7)
    char* gbase = (char*)&g[0][0];
    const u32 wo0 = (u32)(sr0 * 128) + (((u32)q * 16) ^ ((u32)(sr0 & 7) << 4));
    const u32 wo1 = (u32)((64 + sr0) * 128) + (((u32)q * 16) ^ ((u32)(sr0 & 7) << 4));

    // B-fragment read geometry
    const int brow = cg * 32 + col;
    const u32 rrowbase = (u32)(brow * 128);
    const u32 rmask = (u32)(brow & 7) << 4;

    const uint4* wfv = (const uint4*)Wf;

    f32x16 acc{};

    // prefetch gather for k=0
    uint4 p0 = *(const uint4*)(xb + (size_t)j0[0] * CI + q * 8);
    uint4 p1 = *(const uint4*)(xb + (size_t)j1[0] * CI + q * 8);

#pragma unroll
    for (int k = 0; k < KN; ++k) {
        const u32 doff = (u32)(k & 1) * 16384u;

        // prefetch gather for k+1 (hides under this k's barrier+MFMA)
        uint4 np0, np1;
        if (k + 1 < KN) {
            np0 = *(const uint4*)(xb + (size_t)j0[k + 1] * CI + q * 8);
            np1 = *(const uint4*)(xb + (size_t)j1[k + 1] * CI + q * 8);
        }

        // A fragments for this k (L2-resident, coalesced)
        uint4 a0 = wfv[(rg * 28 + k * 4 + 0) * 64 + lane];
        uint4 a1 = wfv[(rg * 28 + k * 4 + 1) * 64 + lane];
        uint4 a2 = wfv[(rg * 28 + k * 4 + 2) * 64 + lane];
        uint4 a3 = wfv[(rg * 28 + k * 4 + 3) * 64 + lane];

        // stage current k into buf (compiler inserts vmcnt wait on p0/p1)
        *(uint4*)(gbase + doff + wo0) = p0;
        *(uint4*)(gbase + doff + wo1) = p1;
        __syncthreads();

        // read B fragments + 4 MFMAs (K=64 channels in 4 steps of 16)
#pragma unroll
        for (int sub = 0; sub < 4; ++sub) {
            u32 off = doff + rrowbase + ((((u32)sub * 32) + (u32)half * 16) ^ rmask);
            uint4 bf = *(const uint4*)(gbase + off);
            uint4 af = (sub == 0) ? a0 : (sub == 1) ? a1 : (sub == 2) ? a2 : a3;
            acc = __builtin_amdgcn_mfma_f32_32x32x16_bf16(
                __builtin_bit_cast(bf16x8, af),
                __builtin_bit_cast(bf16x8, bf), acc, 0, 0, 0);
        }

        if (k + 1 < KN) { p0 = np0; p1 = np1; }
        // no trailing barrier needed: next iter writes the OTHER buffer, and
        // reads of that buffer (iter k-1) were consumed before this barrier.
    }

    // epilogue
    const int v = n0 + cg * 32 + col;
    if (v < NV) {
        float* ob = out + (size_t)b * CO * NV + v;
#pragma unroll
        for (int r = 0; r < 16; ++r) {
            int row = (r & 3) + 8 * (r >> 2) + 4 * half;
            int o = rg * 32 + row;
            ob[(size_t)o * NV] = acc[r] + bias[o];
        }
    }
}

// ---------------------------------------------------------------------------
// Fallback (if ws too small): direct fp32 compute, slow but correct.
// ---------------------------------------------------------------------------
__global__ void naive_conv(const float* __restrict__ x, const int* __restrict__ idx,
                           const float* __restrict__ W, const float* __restrict__ bias,
                           float* __restrict__ out) {
    const int b = blockIdx.y;
    const int n = blockIdx.x * 4 + (threadIdx.x & 3);
    const int o = threadIdx.x >> 2;
    if (n >= NV) return;
    float acc = bias[o];
    const float* xb = x + (size_t)b * CI * NV;
    const float* wo = W + o * KKD;
    for (int k = 0; k < KN; ++k) {
        int j = idx[n * KN + k];
        for (int c = 0; c < CI; ++c)
            acc += xb[(size_t)c * NV + j] * wo[c * KN + k];
    }
    out[((size_t)b * CO + o) * NV + n] = acc;
}

// ---------------------------------------------------------------------------
extern "C" void kernel_launch(void* const* d_in, const int* in_sizes, int n_in,
                              void* d_out, int out_size, void* d_ws, size_t ws_size,
                              hipStream_t stream) {
    const float* x    = (const float*)d_in[0];
    const int*   idx  = (const int*)d_in[1];
    const float* W    = (const float*)d_in[2];
    const float* bias = (const float*)d_in[3];
    float* out = (float*)d_out;

    const size_t xT_bytes = (size_t)BB * NV * CI * 2;       // 41,945,088
    const size_t wf_bytes = (size_t)2 * 28 * 64 * 8 * 2;    // 57,344
    const size_t need = xT_bytes + wf_bytes;

    if (ws_size >= need) {
        u16* xT = (u16*)d_ws;
        u16* Wf = (u16*)((char*)d_ws + xT_bytes);
        transpose_x<<<dim3((NV + 63) / 64, BB), 256, 0, stream>>>(x, xT);
        pack_w<<<dim3(112), 256, 0, stream>>>(W, Wf);
        conv_mfma<<<dim3((NV + 127) / 128, BB), 512, 0, stream>>>(xT, Wf, idx, bias, out);
    } else {
        naive_conv<<<dim3((NV + 3) / 4, BB), 256, 0, stream>>>(x, idx, W, bias, out);
    }
}